// Round 10
// baseline (126.401 us; speedup 1.0000x reference)
//
#include <hip/hip_runtime.h>

// SelfAttention2D: B=4, N=4096, C=256, R=32, fp32 in/out.
// out = gamma * ((softmax_axis1(f g^T) h) w_v) + x.
// 4 kernels: k_prep (weight B-frag pack), k_fgh (projections), k_colsum
// (softmax-axis=1 partial denominators), k_pvout (PV + w_v proj + residual).
// All matmuls on bf16 MFMA 16x16x32. f pre-scaled by log2(e) -> raw v_exp.
// Normalization trick: P = exp2(s')/colsum = exp2(s' + lci), lci = -log2(colsum),
// applied via the MFMA C-operand as a bias -> no scaleh pass, no post-mul,
// and s'+lci <= 0 so exp2 in (0,1] (bf16-safe, overflow-free).
// R6 lesson: grid.sync() ~50us at 512 blocks — block-local fusion only.
// R7 lesson: PV chain (QK->exp->LDS->PV) is latency-bound; need ILP>=4/wave.
// R8 lesson: scattered b16 LDS packs are conflict-expensive; pack once in
// k_prep, stage with contiguous uint4 copies.

#define BB 4
#define NN 4096
#define CC 256
#define RR 32
#define CSEG 4   // n-split for colsum
#define MP 40    // P-tile row stride (ushorts)
#define LOG2E 1.44269504088896340736f

typedef short short8 __attribute__((ext_vector_type(8)));            // 8 bf16
typedef unsigned short ushort8 __attribute__((ext_vector_type(8)));
typedef float floatx4 __attribute__((ext_vector_type(4)));           // MFMA C/D

#define MFMA16 __builtin_amdgcn_mfma_f32_16x16x32_bf16

static __device__ __forceinline__ unsigned short f2bf(float f) {
  union { float f; unsigned u; } v; v.f = f;
  const unsigned r = v.u + 0x7fffu + ((v.u >> 16) & 1u);  // RNE
  return (unsigned short)(r >> 16);
}
// pack trunc-bf16(lo), trunc-bf16(hi) into one uint via v_perm_b32
static __device__ __forceinline__ unsigned bfpack(float lo, float hi) {
  return __builtin_amdgcn_perm(__float_as_uint(hi), __float_as_uint(lo), 0x07060302u);
}

// ------------------------------ k_prep: pack weights into B-frag bf16 layout
__global__ __launch_bounds__(256) void k_prep(
    const float* __restrict__ wf, const float* __restrict__ wg,
    const float* __restrict__ wh, const float* __restrict__ wv,
    unsigned short* __restrict__ wfrag, unsigned short* __restrict__ wvfrag) {
  const int idx = blockIdx.x * 256 + threadIdx.x;  // 0..32767
  const int lane = (idx >> 3) & 63;
  const int j = idx & 7;
  const int col = lane & 15, q = lane >> 4;
  if (idx < 24576) {
    const int mat = idx >> 13;
    const int fid = (idx >> 9) & 15;
    const int kc = fid >> 1, nt = fid & 1;
    const float* w = (mat == 0) ? wf : ((mat == 1) ? wg : wh);
    wfrag[idx] = f2bf(w[(kc * 32 + q * 8 + j) * RR + nt * 16 + col]);
  } else {
    const int r = idx - 24576;
    const int t = (r >> 9) & 15;
    wvfrag[r] = f2bf(wv[(q * 8 + j) * CC + t * 16 + col]);
  }
}

// --------------- k_fgh: f,g,h = x @ {wf,wg,wh}; packed frags staged to LDS
__global__ __launch_bounds__(256) void k_fgh(
    const float* __restrict__ x, const unsigned short* __restrict__ wfrag,
    unsigned short* __restrict__ f16, unsigned short* __restrict__ g16,
    unsigned short* __restrict__ hT16) {
  __shared__ unsigned short wflds[24576];  // 48 KB packed frags
  const int tid = threadIdx.x, lane = tid & 63, wave = tid >> 6;
  const int col = lane & 15, q = lane >> 4;
  {  // conflict-free contiguous stage: 3072 uint4
    const uint4* src = (const uint4*)wfrag;
    uint4* dst = (uint4*)wflds;
#pragma unroll
    for (int i = 0; i < 12; ++i) dst[tid + i * 256] = src[tid + i * 256];
  }
  __syncthreads();
  const int t0 = blockIdx.x * 64 + wave * 16;
  short8 af[8];
  const float* xr = x + (long)(t0 + col) * CC + q * 8;
#pragma unroll
  for (int kc = 0; kc < 8; ++kc) {
    float tmp[8];
    *(float4*)(tmp) = *(const float4*)(xr + kc * 32);
    *(float4*)(tmp + 4) = *(const float4*)(xr + kc * 32 + 4);
    short8 o;
#pragma unroll
    for (int j = 0; j < 8; ++j) o[j] = (short)f2bf(tmp[j]);
    af[kc] = o;
  }
  const floatx4 zero = {0.f, 0.f, 0.f, 0.f};
  floatx4 acc[3][2];
#pragma unroll
  for (int m = 0; m < 3; ++m) { acc[m][0] = zero; acc[m][1] = zero; }
#pragma unroll
  for (int kc = 0; kc < 8; ++kc) {
#pragma unroll
    for (int mat = 0; mat < 3; ++mat) {
#pragma unroll
      for (int nt = 0; nt < 2; ++nt) {
        const short8 bf = *(const short8*)(wflds + (mat * 16 + kc * 2 + nt) * 512 + lane * 8);
        acc[mat][nt] = MFMA16(af[kc], bf, acc[mat][nt], 0, 0, 0);
      }
    }
  }
  const int b = t0 >> 12;
#pragma unroll
  for (int nt = 0; nt < 2; ++nt) {
#pragma unroll
    for (int r = 0; r < 4; ++r) {
      const int tok = t0 + q * 4 + r;
      const int n = nt * 16 + col;
      f16[(long)tok * RR + n] = f2bf(acc[0][nt][r] * LOG2E);
      g16[(long)tok * RR + n] = f2bf(acc[1][nt][r]);
      hT16[((long)b * RR + n) * NN + (tok & (NN - 1))] = f2bf(acc[2][nt][r]);
    }
  }
}

// --------------------- k_colsum: partial colsum[m] = sum_n exp2(s'[n,m])
__global__ __launch_bounds__(256) void k_colsum(
    const unsigned short* __restrict__ f16, const unsigned short* __restrict__ g16,
    float* __restrict__ psum) {
  const int tid = threadIdx.x, lane = tid & 63, wave = tid >> 6;
  const int col = lane & 15, q = lane >> 4;
  const int mblk = blockIdx.x & 31;
  const int b = (blockIdx.x >> 5) & 3;
  const int seg = blockIdx.x >> 7;
  const int m0 = mblk * 128 + wave * 32;
  const short8 bg1 = *(const short8*)(g16 + ((long)(b * NN + m0 + col)) * RR + q * 8);
  const short8 bg2 = *(const short8*)(g16 + ((long)(b * NN + m0 + 16 + col)) * RR + q * 8);
  const floatx4 zero = {0.f, 0.f, 0.f, 0.f};
  float s1 = 0.f, s2 = 0.f;
  const unsigned short* fb = f16 + ((long)b * NN + seg * (NN / CSEG)) * RR;
#pragma unroll 4
  for (int n = 0; n < NN / CSEG; n += 16) {
    const short8 af = *(const short8*)(fb + (long)(n + col) * RR + q * 8);
    const floatx4 d1 = MFMA16(af, bg1, zero, 0, 0, 0);
    const floatx4 d2 = MFMA16(af, bg2, zero, 0, 0, 0);
    s1 += __builtin_amdgcn_exp2f(d1[0]) + __builtin_amdgcn_exp2f(d1[1]) +
          __builtin_amdgcn_exp2f(d1[2]) + __builtin_amdgcn_exp2f(d1[3]);
    s2 += __builtin_amdgcn_exp2f(d2[0]) + __builtin_amdgcn_exp2f(d2[1]) +
          __builtin_amdgcn_exp2f(d2[2]) + __builtin_amdgcn_exp2f(d2[3]);
  }
  s1 += __shfl_xor(s1, 16); s1 += __shfl_xor(s1, 32);
  s2 += __shfl_xor(s2, 16); s2 += __shfl_xor(s2, 32);
  if (lane < 16) {
    psum[(long)seg * (BB * NN) + b * NN + m0 + lane] = s1;
    psum[(long)seg * (BB * NN) + b * NN + m0 + 16 + lane] = s2;
  }
}

// --------- k_pvout: block = 32 tokens; wave w = m-quarter w (ILP-4 PV) +
// LDS partial-y merge + fused y@w_v + gamma*() + x residual.
// Softmax normalization enters as the QK MFMA's C-operand bias lci[m].
#define C_ADDR(TN, TM) (((TN) + col) * MP + (TM) + q * 4)
__global__ __launch_bounds__(256, 4) void k_pvout(
    const unsigned short* __restrict__ f16, const unsigned short* __restrict__ g16,
    const unsigned short* __restrict__ hT16, const unsigned short* __restrict__ wvfrag,
    const float* __restrict__ psum, const float* __restrict__ x,
    const float* __restrict__ gamma, float* __restrict__ out) {
  __shared__ float ylds[4][32 * 36];              // 18 KB: per-wave y partials
  __shared__ unsigned short pt_all[4][32 * MP];   // 10 KB: P^T / epilogue scratch
  __shared__ float lcis[NN];                      // 16 KB: -log2(colsum)
  const int tid = threadIdx.x, lane = tid & 63, wave = tid >> 6;
  const int col = lane & 15, q = lane >> 4;
  const int b = blockIdx.x >> 7;
  const int t0 = (blockIdx.x & 127) * 32;  // token base (in-batch), 32 tokens
  const floatx4 zero = {0.f, 0.f, 0.f, 0.f};
  // prologue: lci[m] = -log2(sum_seg psum) ; consecutive-i -> conflict-free
  for (int i = tid; i < NN; i += 256) {
    float s = 0.f;
#pragma unroll
    for (int sg = 0; sg < CSEG; ++sg) s += psum[(long)sg * (BB * NN) + b * NN + i];
    lcis[i] = -__builtin_amdgcn_logf(s);
  }
  // B-frags of S^T: f rows for the block's 32 tokens (loop-invariant)
  const short8 af1 = *(const short8*)(f16 + ((long)(b * NN + t0 + col)) * RR + q * 8);
  const short8 af2 = *(const short8*)(f16 + ((long)(b * NN + t0 + 16 + col)) * RR + q * 8);
  floatx4 a11 = zero, a12 = zero, a21 = zero, a22 = zero;
  unsigned short* pt = &pt_all[wave][0];
  const unsigned short* gb = g16 + (long)b * NN * RR;
  const unsigned short* hb = hT16 + (long)b * RR * NN;
  const int mq = wave * 1024;  // this wave's m-quarter
  __syncthreads();
#pragma unroll 2
  for (int mi = 0; mi < 1024; mi += 32) {
    const int m0 = mq + mi;
    const short8 bg1 = *(const short8*)(gb + (long)(m0 + col) * RR + q * 8);
    const short8 bg2 = *(const short8*)(gb + (long)(m0 + 16 + col) * RR + q * 8);
    // lci bias as MFMA C-operand (16-lane broadcast b128 reads: free)
    const floatx4 cia = *(const floatx4*)(lcis + m0 + q * 4);
    const floatx4 cib = *(const floatx4*)(lcis + m0 + 16 + q * 4);
    // S^T: A=g(m rows), B=f(n cols) -> lane(q,col): s'[n][m = m0 + q*4+r] + lci
    const floatx4 d00 = MFMA16(bg1, af1, cia, 0, 0, 0);  // n-blk 0, m-blk 0
    const floatx4 d01 = MFMA16(bg2, af1, cib, 0, 0, 0);  // n-blk 0, m-blk 16
    const floatx4 d10 = MFMA16(bg1, af2, cia, 0, 0, 0);  // n-blk 16, m-blk 0
    const floatx4 d11 = MFMA16(bg2, af2, cib, 0, 0, 0);  // n-blk 16, m-blk 16
    // P = exp2(s' + lci) in (0,1]
    float w0, w1, w2, w3;
    w0 = __builtin_amdgcn_exp2f(d00[0]); w1 = __builtin_amdgcn_exp2f(d00[1]);
    w2 = __builtin_amdgcn_exp2f(d00[2]); w3 = __builtin_amdgcn_exp2f(d00[3]);
    *(uint2*)(pt + C_ADDR(0, 0)) = make_uint2(bfpack(w0, w1), bfpack(w2, w3));
    w0 = __builtin_amdgcn_exp2f(d01[0]); w1 = __builtin_amdgcn_exp2f(d01[1]);
    w2 = __builtin_amdgcn_exp2f(d01[2]); w3 = __builtin_amdgcn_exp2f(d01[3]);
    *(uint2*)(pt + C_ADDR(0, 16)) = make_uint2(bfpack(w0, w1), bfpack(w2, w3));
    w0 = __builtin_amdgcn_exp2f(d10[0]); w1 = __builtin_amdgcn_exp2f(d10[1]);
    w2 = __builtin_amdgcn_exp2f(d10[2]); w3 = __builtin_amdgcn_exp2f(d10[3]);
    *(uint2*)(pt + C_ADDR(16, 0)) = make_uint2(bfpack(w0, w1), bfpack(w2, w3));
    w0 = __builtin_amdgcn_exp2f(d11[0]); w1 = __builtin_amdgcn_exp2f(d11[1]);
    w2 = __builtin_amdgcn_exp2f(d11[2]); w3 = __builtin_amdgcn_exp2f(d11[3]);
    *(uint2*)(pt + C_ADDR(16, 16)) = make_uint2(bfpack(w0, w1), bfpack(w2, w3));
    // read back as PV A-frags (same wave, lgkmcnt-ordered)
    const short8 ap1 = *(const short8*)(pt + col * MP + q * 8);
    const short8 ap2 = *(const short8*)(pt + (col + 16) * MP + q * 8);
    const short8 bh1 = *(const short8*)(hb + (long)col * NN + m0 + q * 8);
    const short8 bh2 = *(const short8*)(hb + (long)(col + 16) * NN + m0 + q * 8);
    a11 = MFMA16(ap1, bh1, a11, 0, 0, 0);
    a12 = MFMA16(ap1, bh2, a12, 0, 0, 0);
    a21 = MFMA16(ap2, bh1, a21, 0, 0, 0);
    a22 = MFMA16(ap2, bh2, a22, 0, 0, 0);
  }
  // stash y partial for this m-quarter: [wave][token 0..31][r 0..31]
  {
    float* yp = &ylds[wave][0];
#pragma unroll
    for (int r = 0; r < 4; ++r) {
      yp[(q * 4 + r) * 36 + col] = a11[r];
      yp[(q * 4 + r) * 36 + col + 16] = a12[r];
      yp[(16 + q * 4 + r) * 36 + col] = a21[r];
      yp[(16 + q * 4 + r) * 36 + col + 16] = a22[r];
    }
  }
  __syncthreads();
  // epilogue: wave -> (tile = w&1: 16 tokens, hh = w>>1: 128-channel half);
  // 2 D-tiles per chunk through pt scratch (2304 B <= 2560 B)
  {
    const int tile = wave & 1, hh = wave >> 1;
    float s[8] = {0.f, 0.f, 0.f, 0.f, 0.f, 0.f, 0.f, 0.f};
#pragma unroll
    for (int w2 = 0; w2 < 4; ++w2) {
      const float* yp = &ylds[w2][(tile * 16 + col) * 36 + q * 8];
      const float4 u0 = *(const float4*)yp;
      const float4 u1 = *(const float4*)(yp + 4);
      s[0] += u0.x; s[1] += u0.y; s[2] += u0.z; s[3] += u0.w;
      s[4] += u1.x; s[5] += u1.y; s[6] += u1.z; s[7] += u1.w;
    }
    short8 ay;
#pragma unroll
    for (int j = 0; j < 8; ++j) ay[j] = (short)f2bf(s[j]);
    const float gm = gamma[0];
    float* sc = (float*)pt;  // per-wave scratch, 16 x 36 floats
    const int row = lane >> 2, c4 = (lane & 3) * 4;
#pragma unroll
    for (int tp = 0; tp < 8; tp += 2) {
      const short8 bw0 = *(const short8*)(wvfrag + (hh * 8 + tp) * 512 + lane * 8);
      const short8 bw1 = *(const short8*)(wvfrag + (hh * 8 + tp + 1) * 512 + lane * 8);
      const floatx4 d0 = MFMA16(ay, bw0, zero, 0, 0, 0);
      const floatx4 d1 = MFMA16(ay, bw1, zero, 0, 0, 0);
#pragma unroll
      for (int r = 0; r < 4; ++r) {
        sc[(q * 4 + r) * 36 + col] = d0[r];
        sc[(q * 4 + r) * 36 + col + 16] = d1[r];
      }
      // same-wave readback, row-major -> coalesced float4 global I/O
#pragma unroll
      for (int j = 0; j < 2; ++j) {
        const float4 v = *(const float4*)(sc + row * 36 + c4 + j * 16);
        const long gidx = (long)(b * NN + t0 + tile * 16 + row) * CC +
                          hh * 128 + tp * 16 + j * 16 + c4;
        const float4 xv = *(const float4*)(x + gidx);
        float4 o;
        o.x = gm * v.x + xv.x; o.y = gm * v.y + xv.y;
        o.z = gm * v.z + xv.z; o.w = gm * v.w + xv.w;
        *(float4*)(out + gidx) = o;
      }
    }
  }
}

extern "C" void kernel_launch(void* const* d_in, const int* in_sizes, int n_in,
                              void* d_out, int out_size, void* d_ws, size_t ws_size,
                              hipStream_t stream) {
  const float* x = (const float*)d_in[0];
  const float* wf = (const float*)d_in[1];
  const float* wg = (const float*)d_in[2];
  const float* wh = (const float*)d_in[3];
  const float* wv = (const float*)d_in[4];
  const float* gamma = (const float*)d_in[5];
  float* out = (float*)d_out;

  unsigned short* f16 = (unsigned short*)d_ws;           // B*N*R (x LOG2E)
  unsigned short* g16 = f16 + (long)BB * NN * RR;        // B*N*R
  unsigned short* hT16 = g16 + (long)BB * NN * RR;       // B*R*N
  unsigned short* wfrag = hT16 + (long)BB * NN * RR;     // 24576
  unsigned short* wvfrag = wfrag + 24576;                // 8192
  float* psum = (float*)(wvfrag + 8192);                 // CSEG*B*N

  k_prep<<<128, 256, 0, stream>>>(wf, wg, wh, wv, wfrag, wvfrag);
  k_fgh<<<BB * NN / 64, 256, 0, stream>>>(x, wfrag, f16, g16, hT16);
  k_colsum<<<CSEG * BB * 32, 256, 0, stream>>>(f16, g16, psum);
  k_pvout<<<BB * 128, 256, 0, stream>>>(f16, g16, hT16, wvfrag, psum, x, gamma, out);
}

// Round 11
// 123.661 us; speedup vs baseline: 1.0222x; 1.0222x over previous
//
#include <hip/hip_runtime.h>

// SelfAttention2D: B=4, N=4096, C=256, R=32, fp32 in/out.
// out = gamma * ((softmax_axis1(f g^T) h) w_v) + x.
// 5 kernels: k_prep (weight B-frag pack), k_fgh (projections), k_colsum
// (softmax-axis=1 partial denominators), k_scaleh (fold 1/colsum into h),
// k_pvout (PV + w_v projection + residual; 512-thr blocks, 8 m-eighth waves).
// All matmuls on bf16 MFMA 16x16x32. f pre-scaled by log2(e) -> raw v_exp.
// |s|*log2e < 64 << 128 so exp2 needs no max pass; exp2 <= 2^63 fits bf16;
// 1/colsum folded into h so PV needs no per-element scaling.
// R6 lesson: grid.sync() ~50us at 512 blocks — block-local fusion only.
// R7 lesson: PV chain (QK->exp->LDS->PV) is latency-bound; keep ILP-4/wave.
// R8 lesson: scattered b16 LDS packs are conflict-expensive; pack in k_prep.
// R10 lesson: C-operand lci bias traded a 1.5us kernel for per-block lcis
// merge + LDS; net negative. Keep scaleh.
// R11: pvout TLP 2->4 waves/SIMD via 512-thread blocks (8 m-eighth waves).

#define BB 4
#define NN 4096
#define CC 256
#define RR 32
#define CSEG 4   // n-split for colsum
#define MP 40    // P-tile row stride (ushorts)
#define LOG2E 1.44269504088896340736f

typedef short short8 __attribute__((ext_vector_type(8)));            // 8 bf16
typedef unsigned short ushort8 __attribute__((ext_vector_type(8)));
typedef float floatx4 __attribute__((ext_vector_type(4)));           // MFMA C/D

#define MFMA16 __builtin_amdgcn_mfma_f32_16x16x32_bf16

static __device__ __forceinline__ unsigned short f2bf(float f) {
  union { float f; unsigned u; } v; v.f = f;
  const unsigned r = v.u + 0x7fffu + ((v.u >> 16) & 1u);  // RNE
  return (unsigned short)(r >> 16);
}
// pack trunc-bf16(lo), trunc-bf16(hi) into one uint via v_perm_b32
static __device__ __forceinline__ unsigned bfpack(float lo, float hi) {
  return __builtin_amdgcn_perm(__float_as_uint(hi), __float_as_uint(lo), 0x07060302u);
}

// ------------------------------ k_prep: pack weights into B-frag bf16 layout
__global__ __launch_bounds__(256) void k_prep(
    const float* __restrict__ wf, const float* __restrict__ wg,
    const float* __restrict__ wh, const float* __restrict__ wv,
    unsigned short* __restrict__ wfrag, unsigned short* __restrict__ wvfrag) {
  const int idx = blockIdx.x * 256 + threadIdx.x;  // 0..32767
  const int lane = (idx >> 3) & 63;
  const int j = idx & 7;
  const int col = lane & 15, q = lane >> 4;
  if (idx < 24576) {
    const int mat = idx >> 13;
    const int fid = (idx >> 9) & 15;
    const int kc = fid >> 1, nt = fid & 1;
    const float* w = (mat == 0) ? wf : ((mat == 1) ? wg : wh);
    wfrag[idx] = f2bf(w[(kc * 32 + q * 8 + j) * RR + nt * 16 + col]);
  } else {
    const int r = idx - 24576;
    const int t = (r >> 9) & 15;
    wvfrag[r] = f2bf(wv[(q * 8 + j) * CC + t * 16 + col]);
  }
}

// --------------- k_fgh: f,g,h = x @ {wf,wg,wh}; packed frags staged to LDS
__global__ __launch_bounds__(256) void k_fgh(
    const float* __restrict__ x, const unsigned short* __restrict__ wfrag,
    unsigned short* __restrict__ f16, unsigned short* __restrict__ g16,
    unsigned short* __restrict__ hT16) {
  __shared__ unsigned short wflds[24576];  // 48 KB packed frags
  const int tid = threadIdx.x, lane = tid & 63, wave = tid >> 6;
  const int col = lane & 15, q = lane >> 4;
  {  // conflict-free contiguous stage: 3072 uint4
    const uint4* src = (const uint4*)wfrag;
    uint4* dst = (uint4*)wflds;
#pragma unroll
    for (int i = 0; i < 12; ++i) dst[tid + i * 256] = src[tid + i * 256];
  }
  __syncthreads();
  const int t0 = blockIdx.x * 64 + wave * 16;
  short8 af[8];
  const float* xr = x + (long)(t0 + col) * CC + q * 8;
#pragma unroll
  for (int kc = 0; kc < 8; ++kc) {
    float tmp[8];
    *(float4*)(tmp) = *(const float4*)(xr + kc * 32);
    *(float4*)(tmp + 4) = *(const float4*)(xr + kc * 32 + 4);
    short8 o;
#pragma unroll
    for (int j = 0; j < 8; ++j) o[j] = (short)f2bf(tmp[j]);
    af[kc] = o;
  }
  const floatx4 zero = {0.f, 0.f, 0.f, 0.f};
  floatx4 acc[3][2];
#pragma unroll
  for (int m = 0; m < 3; ++m) { acc[m][0] = zero; acc[m][1] = zero; }
#pragma unroll
  for (int kc = 0; kc < 8; ++kc) {
#pragma unroll
    for (int mat = 0; mat < 3; ++mat) {
#pragma unroll
      for (int nt = 0; nt < 2; ++nt) {
        const short8 bf = *(const short8*)(wflds + (mat * 16 + kc * 2 + nt) * 512 + lane * 8);
        acc[mat][nt] = MFMA16(af[kc], bf, acc[mat][nt], 0, 0, 0);
      }
    }
  }
  const int b = t0 >> 12;
#pragma unroll
  for (int nt = 0; nt < 2; ++nt) {
#pragma unroll
    for (int r = 0; r < 4; ++r) {
      const int tok = t0 + q * 4 + r;
      const int n = nt * 16 + col;
      f16[(long)tok * RR + n] = f2bf(acc[0][nt][r] * LOG2E);
      g16[(long)tok * RR + n] = f2bf(acc[1][nt][r]);
      hT16[((long)b * RR + n) * NN + (tok & (NN - 1))] = f2bf(acc[2][nt][r]);
    }
  }
}

// --------------------- k_colsum: partial colsum[m] = sum_n exp2(s'[n,m])
__global__ __launch_bounds__(256) void k_colsum(
    const unsigned short* __restrict__ f16, const unsigned short* __restrict__ g16,
    float* __restrict__ psum) {
  const int tid = threadIdx.x, lane = tid & 63, wave = tid >> 6;
  const int col = lane & 15, q = lane >> 4;
  const int mblk = blockIdx.x & 31;
  const int b = (blockIdx.x >> 5) & 3;
  const int seg = blockIdx.x >> 7;
  const int m0 = mblk * 128 + wave * 32;
  const short8 bg1 = *(const short8*)(g16 + ((long)(b * NN + m0 + col)) * RR + q * 8);
  const short8 bg2 = *(const short8*)(g16 + ((long)(b * NN + m0 + 16 + col)) * RR + q * 8);
  const floatx4 zero = {0.f, 0.f, 0.f, 0.f};
  float s1 = 0.f, s2 = 0.f;
  const unsigned short* fb = f16 + ((long)b * NN + seg * (NN / CSEG)) * RR;
#pragma unroll 4
  for (int n = 0; n < NN / CSEG; n += 16) {
    const short8 af = *(const short8*)(fb + (long)(n + col) * RR + q * 8);
    const floatx4 d1 = MFMA16(af, bg1, zero, 0, 0, 0);
    const floatx4 d2 = MFMA16(af, bg2, zero, 0, 0, 0);
    s1 += __builtin_amdgcn_exp2f(d1[0]) + __builtin_amdgcn_exp2f(d1[1]) +
          __builtin_amdgcn_exp2f(d1[2]) + __builtin_amdgcn_exp2f(d1[3]);
    s2 += __builtin_amdgcn_exp2f(d2[0]) + __builtin_amdgcn_exp2f(d2[1]) +
          __builtin_amdgcn_exp2f(d2[2]) + __builtin_amdgcn_exp2f(d2[3]);
  }
  s1 += __shfl_xor(s1, 16); s1 += __shfl_xor(s1, 32);
  s2 += __shfl_xor(s2, 16); s2 += __shfl_xor(s2, 32);
  if (lane < 16) {
    psum[(long)seg * (BB * NN) + b * NN + m0 + lane] = s1;
    psum[(long)seg * (BB * NN) + b * NN + m0 + 16 + lane] = s2;
  }
}

// --------------- k_scaleh: hT'[b][r][m] = hT[b][r][m] / colsum[b][m]
__global__ __launch_bounds__(256) void k_scaleh(
    const float* __restrict__ psum, unsigned short* __restrict__ hT16) {
  const long i8 = ((long)blockIdx.x * 256 + threadIdx.x) * 8;
  const int b = (int)(i8 >> 17);       // / (RR*NN)
  const int m = (int)(i8 & (NN - 1));
  float cs[8] = {0.f, 0.f, 0.f, 0.f, 0.f, 0.f, 0.f, 0.f};
#pragma unroll
  for (int sg = 0; sg < CSEG; ++sg) {
    const float* p = psum + (long)sg * (BB * NN) + b * NN + m;
    const float4 a = *(const float4*)p;
    const float4 c = *(const float4*)(p + 4);
    cs[0] += a.x; cs[1] += a.y; cs[2] += a.z; cs[3] += a.w;
    cs[4] += c.x; cs[5] += c.y; cs[6] += c.z; cs[7] += c.w;
  }
  const ushort8 hv = *(const ushort8*)(hT16 + i8);
  ushort8 o;
#pragma unroll
  for (int j = 0; j < 8; ++j) {
    const float h = __uint_as_float(((unsigned)hv[j]) << 16);
    o[j] = f2bf(h * __builtin_amdgcn_rcpf(cs[j]));
  }
  *(ushort8*)(hT16 + i8) = o;
}

// --------- k_pvout: 512-thread block = 32 tokens; 8 waves = m-eighths
// (ILP-4 PV per wave) + LDS partial-y merge + fused y@w_v + residual.
// 2 blocks/CU x 8 waves = 16 waves/CU = 4 waves/SIMD (vs 2 in the 256-thr
// version) — doubles latency-hiding TLP for the QK->exp->LDS->PV chain.
#define C_ADDR(TN, TM) (((TN) + col) * MP + (TM) + q * 4)
__global__ __launch_bounds__(512, 4) void k_pvout(
    const unsigned short* __restrict__ f16, const unsigned short* __restrict__ g16,
    const unsigned short* __restrict__ hT16, const unsigned short* __restrict__ wvfrag,
    const float* __restrict__ x, const float* __restrict__ gamma,
    float* __restrict__ out) {
  __shared__ float ylds[8][32 * 36];              // 36 KB: per-wave y partials
  __shared__ unsigned short pt_all[8][32 * MP];   // 20.5 KB: P^T / epi scratch
  const int tid = threadIdx.x, lane = tid & 63, wave = tid >> 6;  // 0..7
  const int col = lane & 15, q = lane >> 4;
  const int b = blockIdx.x >> 7;
  const int t0 = (blockIdx.x & 127) * 32;  // token base (in-batch), 32 tokens
  const floatx4 zero = {0.f, 0.f, 0.f, 0.f};
  // B-frags of S^T: f rows for the block's 32 tokens (loop-invariant)
  const short8 af1 = *(const short8*)(f16 + ((long)(b * NN + t0 + col)) * RR + q * 8);
  const short8 af2 = *(const short8*)(f16 + ((long)(b * NN + t0 + 16 + col)) * RR + q * 8);
  floatx4 a11 = zero, a12 = zero, a21 = zero, a22 = zero;
  unsigned short* pt = &pt_all[wave][0];
  const unsigned short* gb = g16 + (long)b * NN * RR;
  const unsigned short* hb = hT16 + (long)b * RR * NN;
  const int mq = wave * 512;  // this wave's m-eighth
#pragma unroll 2
  for (int mi = 0; mi < 512; mi += 32) {
    const int m0 = mq + mi;
    const short8 bg1 = *(const short8*)(gb + (long)(m0 + col) * RR + q * 8);
    const short8 bg2 = *(const short8*)(gb + (long)(m0 + 16 + col) * RR + q * 8);
    // S^T: A=g(m rows), B=f(n cols) -> lane(q,col): s'[n][m = m0 + q*4+r]
    const floatx4 d00 = MFMA16(bg1, af1, zero, 0, 0, 0);  // n-blk 0, m-blk 0
    const floatx4 d01 = MFMA16(bg2, af1, zero, 0, 0, 0);  // n-blk 0, m-blk 16
    const floatx4 d10 = MFMA16(bg1, af2, zero, 0, 0, 0);  // n-blk 16, m-blk 0
    const floatx4 d11 = MFMA16(bg2, af2, zero, 0, 0, 0);  // n-blk 16, m-blk 16
    // P' = exp2(s') (1/colsum already folded into h')
    float w0, w1, w2, w3;
    w0 = __builtin_amdgcn_exp2f(d00[0]); w1 = __builtin_amdgcn_exp2f(d00[1]);
    w2 = __builtin_amdgcn_exp2f(d00[2]); w3 = __builtin_amdgcn_exp2f(d00[3]);
    *(uint2*)(pt + C_ADDR(0, 0)) = make_uint2(bfpack(w0, w1), bfpack(w2, w3));
    w0 = __builtin_amdgcn_exp2f(d01[0]); w1 = __builtin_amdgcn_exp2f(d01[1]);
    w2 = __builtin_amdgcn_exp2f(d01[2]); w3 = __builtin_amdgcn_exp2f(d01[3]);
    *(uint2*)(pt + C_ADDR(0, 16)) = make_uint2(bfpack(w0, w1), bfpack(w2, w3));
    w0 = __builtin_amdgcn_exp2f(d10[0]); w1 = __builtin_amdgcn_exp2f(d10[1]);
    w2 = __builtin_amdgcn_exp2f(d10[2]); w3 = __builtin_amdgcn_exp2f(d10[3]);
    *(uint2*)(pt + C_ADDR(16, 0)) = make_uint2(bfpack(w0, w1), bfpack(w2, w3));
    w0 = __builtin_amdgcn_exp2f(d11[0]); w1 = __builtin_amdgcn_exp2f(d11[1]);
    w2 = __builtin_amdgcn_exp2f(d11[2]); w3 = __builtin_amdgcn_exp2f(d11[3]);
    *(uint2*)(pt + C_ADDR(16, 16)) = make_uint2(bfpack(w0, w1), bfpack(w2, w3));
    // read back as PV A-frags (same wave, lgkmcnt-ordered)
    const short8 ap1 = *(const short8*)(pt + col * MP + q * 8);
    const short8 ap2 = *(const short8*)(pt + (col + 16) * MP + q * 8);
    const short8 bh1 = *(const short8*)(hb + (long)col * NN + m0 + q * 8);
    const short8 bh2 = *(const short8*)(hb + (long)(col + 16) * NN + m0 + q * 8);
    a11 = MFMA16(ap1, bh1, a11, 0, 0, 0);
    a12 = MFMA16(ap1, bh2, a12, 0, 0, 0);
    a21 = MFMA16(ap2, bh1, a21, 0, 0, 0);
    a22 = MFMA16(ap2, bh2, a22, 0, 0, 0);
  }
  // stash y partial for this m-eighth: [wave][token 0..31][r 0..31]
  {
    float* yp = &ylds[wave][0];
#pragma unroll
    for (int r = 0; r < 4; ++r) {
      yp[(q * 4 + r) * 36 + col] = a11[r];
      yp[(q * 4 + r) * 36 + col + 16] = a12[r];
      yp[(16 + q * 4 + r) * 36 + col] = a21[r];
      yp[(16 + q * 4 + r) * 36 + col + 16] = a22[r];
    }
  }
  __syncthreads();
  // epilogue: wave -> (tile = w&1: 16 tokens, hh = w>>1: 64-channel quarter);
  // 2 D-tiles per chunk through pt scratch (2304 B <= 2560 B)
  {
    const int tile = wave & 1, hh = wave >> 1;  // hh in 0..3
    float s[8] = {0.f, 0.f, 0.f, 0.f, 0.f, 0.f, 0.f, 0.f};
#pragma unroll
    for (int w2 = 0; w2 < 8; ++w2) {
      const float* yp = &ylds[w2][(tile * 16 + col) * 36 + q * 8];
      const float4 u0 = *(const float4*)yp;
      const float4 u1 = *(const float4*)(yp + 4);
      s[0] += u0.x; s[1] += u0.y; s[2] += u0.z; s[3] += u0.w;
      s[4] += u1.x; s[5] += u1.y; s[6] += u1.z; s[7] += u1.w;
    }
    short8 ay;
#pragma unroll
    for (int j = 0; j < 8; ++j) ay[j] = (short)f2bf(s[j]);
    const float gm = gamma[0];
    float* sc = (float*)pt;  // per-wave scratch, 16 x 36 floats
    const int row = lane >> 2, c4 = (lane & 3) * 4;
#pragma unroll
    for (int tp = 0; tp < 4; tp += 2) {
      const short8 bw0 = *(const short8*)(wvfrag + (hh * 4 + tp) * 512 + lane * 8);
      const short8 bw1 = *(const short8*)(wvfrag + (hh * 4 + tp + 1) * 512 + lane * 8);
      const floatx4 d0 = MFMA16(ay, bw0, zero, 0, 0, 0);
      const floatx4 d1 = MFMA16(ay, bw1, zero, 0, 0, 0);
#pragma unroll
      for (int r = 0; r < 4; ++r) {
        sc[(q * 4 + r) * 36 + col] = d0[r];
        sc[(q * 4 + r) * 36 + col + 16] = d1[r];
      }
      // same-wave readback, row-major -> coalesced float4 global I/O
#pragma unroll
      for (int j = 0; j < 2; ++j) {
        const float4 v = *(const float4*)(sc + row * 36 + c4 + j * 16);
        const long gidx = (long)(b * NN + t0 + tile * 16 + row) * CC +
                          hh * 64 + tp * 16 + j * 16 + c4;
        const float4 xv = *(const float4*)(x + gidx);
        float4 o;
        o.x = gm * v.x + xv.x; o.y = gm * v.y + xv.y;
        o.z = gm * v.z + xv.z; o.w = gm * v.w + xv.w;
        *(float4*)(out + gidx) = o;
      }
    }
  }
}

extern "C" void kernel_launch(void* const* d_in, const int* in_sizes, int n_in,
                              void* d_out, int out_size, void* d_ws, size_t ws_size,
                              hipStream_t stream) {
  const float* x = (const float*)d_in[0];
  const float* wf = (const float*)d_in[1];
  const float* wg = (const float*)d_in[2];
  const float* wh = (const float*)d_in[3];
  const float* wv = (const float*)d_in[4];
  const float* gamma = (const float*)d_in[5];
  float* out = (float*)d_out;

  unsigned short* f16 = (unsigned short*)d_ws;           // B*N*R (x LOG2E)
  unsigned short* g16 = f16 + (long)BB * NN * RR;        // B*N*R
  unsigned short* hT16 = g16 + (long)BB * NN * RR;       // B*R*N (scaled in-place)
  unsigned short* wfrag = hT16 + (long)BB * NN * RR;     // 24576
  unsigned short* wvfrag = wfrag + 24576;                // 8192
  float* psum = (float*)(wvfrag + 8192);                 // CSEG*B*N

  k_prep<<<128, 256, 0, stream>>>(wf, wg, wh, wv, wfrag, wvfrag);
  k_fgh<<<BB * NN / 64, 256, 0, stream>>>(x, wfrag, f16, g16, hT16);
  k_colsum<<<CSEG * BB * 32, 256, 0, stream>>>(f16, g16, psum);
  k_scaleh<<<BB * RR * NN / 2048, 256, 0, stream>>>(psum, hT16);
  k_pvout<<<BB * 128, 512, 0, stream>>>(f16, g16, hT16, wvfrag, x, gamma, out);
}